// Round 8
// baseline (39.982 us; speedup 1.0000x reference)
//
#include <hip/hip_runtime.h>
#include <math.h>

#define NLEV 44
#define NDENSE 15          // levels 0..14 dense ((res+1)^2 <= 1024); host-verified
#define IMG 178
#define NPTS (IMG*IMG)
#define HASH_SIZE 1024
#define PRIME 2654435761u
#define BLOCK 1024
#define PTS_PER_BLOCK (2*BLOCK)

typedef __attribute__((ext_vector_type(2))) float f32x2;

struct LevelParams {
    int res[NLEV];
    int offs[NLEV];
    int total;
};

// acc (f32x2) += a * b, b wave-uniform (SGPR pair)
#define PKFMA_S(acc, a, b) \
    asm("v_pk_fma_f32 %0, %1, %2, %0" : "+v"(acc) : "v"(a), "s"(b))

// ---- pre-kernel: transpose W1 [b][o][l] -> [b][l][o] into d_ws ----
__global__ __launch_bounds__(1024) void transpose_w1(const float* __restrict__ w1,
                                                     float* __restrict__ w1t) {
    const int b = blockIdx.x;
    const int i = threadIdx.x;          // i = l*16 + o
    if (i < 16 * NLEV) {
        const int l = i >> 4, o = i & 15;
        w1t[(size_t)b * 16 * NLEV + i] = w1[(size_t)b * 16 * NLEV + o * NLEV + l];
    }
}

// ---- grouped dense levels: load 2pts x CNT levels x 4 corners, then consume ----
template<int L0, int CNT, bool TP>
__device__ __forceinline__ void dense_group(
    const LevelParams& lp, const float* __restrict__ sCB,
    const float* __restrict__ w1b,
    float2 xy0, float2 xy1, f32x2* __restrict__ h1a, f32x2* __restrict__ h1b)
{
    float v[2][CNT][4];
    float fr[2][CNT][2];
#pragma unroll
    for (int i = 0; i < CNT; ++i) {
        const int l = L0 + i;
        const int res = lp.res[l];
        const int st  = res + 1;
        const int off = lp.offs[l];
        const float rf = (float)res;
#pragma unroll
        for (int p = 0; p < 2; ++p) {
            const float2 xy = p ? xy1 : xy0;
            const float sx = xy.x * rf, sy = xy.y * rf;
            const int ix0 = (int)sx, iy0 = (int)sy;   // x in [0,1): trunc==floor, no clamp
            fr[p][i][0] = sx - (float)ix0;
            fr[p][i][1] = sy - (float)iy0;
            const int r0 = off + iy0 * st + ix0;
            v[p][i][0] = sCB[r0];
            v[p][i][1] = sCB[r0 + 1];
            v[p][i][2] = sCB[r0 + st];
            v[p][i][3] = sCB[r0 + st + 1];
        }
    }
#pragma unroll
    for (int i = 0; i < CNT; ++i) {
        const int l = L0 + i;
        f32x2 wlv[8];
        if constexpr (TP) {
            const f32x2* wp = (const f32x2*)(w1b + l * 16);
#pragma unroll
            for (int j = 0; j < 8; ++j) wlv[j] = wp[j];
        } else {
#pragma unroll
            for (int j = 0; j < 8; ++j) {
                wlv[j].x = w1b[(2 * j) * NLEV + l];
                wlv[j].y = w1b[(2 * j + 1) * NLEV + l];
            }
        }
#pragma unroll
        for (int p = 0; p < 2; ++p) {
            f32x2* h1 = p ? h1b : h1a;
            const float vx0 = fmaf(fr[p][i][0], v[p][i][1] - v[p][i][0], v[p][i][0]);
            const float vx1 = fmaf(fr[p][i][0], v[p][i][3] - v[p][i][2], v[p][i][2]);
            const float feat = fmaf(fr[p][i][1], vx1 - vx0, vx0);
            f32x2 f2; f2.x = feat; f2.y = feat;
#pragma unroll
            for (int j = 0; j < 8; ++j) PKFMA_S(h1[j], f2, wlv[j]);
        }
    }
}

// ---- grouped hashed levels ----
template<int L0, int CNT, bool TP>
__device__ __forceinline__ void hash_group(
    const LevelParams& lp, const float* __restrict__ sCB,
    const float* __restrict__ w1b,
    float2 xy0, float2 xy1, f32x2* __restrict__ h1a, f32x2* __restrict__ h1b)
{
    float v[2][CNT][4];
    float fr[2][CNT][2];
#pragma unroll
    for (int i = 0; i < CNT; ++i) {
        const int l = L0 + i;
        const int off = lp.offs[l];
        const float rf = (float)lp.res[l];
#pragma unroll
        for (int p = 0; p < 2; ++p) {
            const float2 xy = p ? xy1 : xy0;
            const float sx = xy.x * rf, sy = xy.y * rf;
            const int ix0 = (int)sx, iy0 = (int)sy;
            fr[p][i][0] = sx - (float)ix0;
            fr[p][i][1] = sy - (float)iy0;
            const unsigned px0 = (unsigned)ix0, px1 = px0 + 1u;
            const unsigned py0 = (unsigned)iy0 * PRIME, py1 = py0 + PRIME;
            const int i00 = (int)((px0 ^ py0) & (HASH_SIZE - 1));
            const int i01 = (int)((px0 ^ py1) & (HASH_SIZE - 1));
            const int i10 = (int)((px1 ^ py0) & (HASH_SIZE - 1));
            const int i11 = (int)((px1 ^ py1) & (HASH_SIZE - 1));
            v[p][i][0] = sCB[off + i00];
            v[p][i][1] = sCB[off + i10];
            v[p][i][2] = sCB[off + i01];
            v[p][i][3] = sCB[off + i11];
        }
    }
#pragma unroll
    for (int i = 0; i < CNT; ++i) {
        const int l = L0 + i;
        f32x2 wlv[8];
        if constexpr (TP) {
            const f32x2* wp = (const f32x2*)(w1b + l * 16);
#pragma unroll
            for (int j = 0; j < 8; ++j) wlv[j] = wp[j];
        } else {
#pragma unroll
            for (int j = 0; j < 8; ++j) {
                wlv[j].x = w1b[(2 * j) * NLEV + l];
                wlv[j].y = w1b[(2 * j + 1) * NLEV + l];
            }
        }
#pragma unroll
        for (int p = 0; p < 2; ++p) {
            f32x2* h1 = p ? h1b : h1a;
            const float vx0 = fmaf(fr[p][i][0], v[p][i][1] - v[p][i][0], v[p][i][0]);
            const float vx1 = fmaf(fr[p][i][0], v[p][i][3] - v[p][i][2], v[p][i][2]);
            const float feat = fmaf(fr[p][i][1], vx1 - vx0, vx0);
            f32x2 f2; f2.x = feat; f2.y = feat;
#pragma unroll
            for (int j = 0; j < 8; ++j) PKFMA_S(h1[j], f2, wlv[j]);
        }
    }
}

template<bool TP>
__global__ __launch_bounds__(BLOCK) void shacira_kernel(
    const float* __restrict__ x, const float* __restrict__ codebook,
    const float* __restrict__ w1, const float* __restrict__ w1t,
    const float* __restrict__ w2, const float* __restrict__ w3,
    float* __restrict__ out, LevelParams lp)
{
    extern __shared__ float sCB[];      // codebook only (~151 KB)
    const int total = lp.total;
    const int tid = threadIdx.x;
    const int b = blockIdx.y;

    // ---- stage codebook (float4, coalesced) ----
    {
        const float* cbg = codebook + (size_t)b * total;
        const float4* src = (const float4*)cbg;
        float4* dst = (float4*)sCB;
        const int n4 = total >> 2;
        for (int i = tid; i < n4; i += BLOCK) dst[i] = src[i];
        for (int i = (n4 << 2) + tid; i < total; i += BLOCK) sCB[i] = cbg[i];
    }
    __syncthreads();

    const float* w1b = TP ? (w1t + (size_t)b * 16 * NLEV) : (w1 + (size_t)b * 16 * NLEV);
    const float* w2b = w2 + (size_t)b * 256;
    const float* w3b = w3 + (size_t)b * 48;

    const int n0 = blockIdx.x * PTS_PER_BLOCK + tid;
    const int n1 = n0 + BLOCK;
    const bool valid0 = n0 < NPTS;
    const bool valid1 = n1 < NPTS;
    const float2* xg = (const float2*)x + (size_t)b * NPTS;
    float2 xy0 = valid0 ? xg[n0] : make_float2(0.f, 0.f);
    float2 xy1 = valid1 ? xg[n1] : make_float2(0.f, 0.f);

    f32x2 h1a[8], h1b[8];
#pragma unroll
    for (int j = 0; j < 8; ++j) {
        h1a[j].x = 0.f; h1a[j].y = 0.f;
        h1b[j].x = 0.f; h1b[j].y = 0.f;
    }

    // dense levels 0..14 (groups of 4,4,4,3)
    dense_group<0, 4, TP>(lp, sCB, w1b, xy0, xy1, h1a, h1b);
    dense_group<4, 4, TP>(lp, sCB, w1b, xy0, xy1, h1a, h1b);
    dense_group<8, 4, TP>(lp, sCB, w1b, xy0, xy1, h1a, h1b);
    dense_group<12, 3, TP>(lp, sCB, w1b, xy0, xy1, h1a, h1b);
    // hashed levels 15..43 (7 groups of 4 + 1)
    hash_group<15, 4, TP>(lp, sCB, w1b, xy0, xy1, h1a, h1b);
    hash_group<19, 4, TP>(lp, sCB, w1b, xy0, xy1, h1a, h1b);
    hash_group<23, 4, TP>(lp, sCB, w1b, xy0, xy1, h1a, h1b);
    hash_group<27, 4, TP>(lp, sCB, w1b, xy0, xy1, h1a, h1b);
    hash_group<31, 4, TP>(lp, sCB, w1b, xy0, xy1, h1a, h1b);
    hash_group<35, 4, TP>(lp, sCB, w1b, xy0, xy1, h1a, h1b);
    hash_group<39, 4, TP>(lp, sCB, w1b, xy0, xy1, h1a, h1b);
    hash_group<43, 1, TP>(lp, sCB, w1b, xy0, xy1, h1a, h1b);

    // ---- MLP (per point) ----
    auto mlp = [&](f32x2* h1, int n, bool valid) {
        if (!valid) return;
#pragma unroll
        for (int j = 0; j < 8; ++j) {
            h1[j].x = fmaxf(h1[j].x, 0.f);
            h1[j].y = fmaxf(h1[j].y, 0.f);
        }
        float h2[16];
#pragma unroll
        for (int o = 0; o < 16; ++o) {
            const f32x2* w2v = (const f32x2*)(w2b + o * 16);
            f32x2 acc; acc.x = 0.f; acc.y = 0.f;
#pragma unroll
            for (int k = 0; k < 8; ++k) PKFMA_S(acc, h1[k], w2v[k]);
            h2[o] = fmaxf(acc.x + acc.y, 0.f);
        }
        f32x2 h2v[8];
#pragma unroll
        for (int j = 0; j < 8; ++j) { h2v[j].x = h2[2 * j]; h2v[j].y = h2[2 * j + 1]; }
        float rgb[3];
#pragma unroll
        for (int c = 0; c < 3; ++c) {
            const f32x2* w3v = (const f32x2*)(w3b + c * 16);
            f32x2 acc; acc.x = 0.f; acc.y = 0.f;
#pragma unroll
            for (int k = 0; k < 8; ++k) PKFMA_S(acc, h2v[k], w3v[k]);
            rgb[c] = 1.f / (1.f + expf(-(acc.x + acc.y)));
        }
        float* op = out + ((size_t)b * NPTS + n) * 3;
        op[0] = rgb[0]; op[1] = rgb[1]; op[2] = rgb[2];
    };
    mlp(h1a, n0, valid0);
    mlp(h1b, n1, valid1);
}

extern "C" void kernel_launch(void* const* d_in, const int* in_sizes, int n_in,
                              void* d_out, int out_size, void* d_ws, size_t ws_size,
                              hipStream_t stream) {
    const float* x        = (const float*)d_in[0];
    const float* codebook = (const float*)d_in[1];
    const float* w1       = (const float*)d_in[2];
    const float* w2       = (const float*)d_in[3];
    const float* w3       = (const float*)d_in[4];
    float* out = (float*)d_out;

    const int B = in_sizes[0] / (NPTS * 2);

    LevelParams lp;
    int off = 0;
    for (int l = 0; l < NLEV; ++l) {
        const double r = 16.0 * pow(128.0 / 16.0, (double)l / (double)(NLEV - 1));
        const int res = (int)llrint(r);
        lp.res[l] = res;
        lp.offs[l] = off;
        const int sz = ((long long)(res + 1) * (res + 1) <= HASH_SIZE)
                           ? (res + 1) * (res + 1) : HASH_SIZE;
        off += sz;
    }
    lp.total = off;

    const size_t smemBytes = (size_t)lp.total * 4;
    const size_t w1tBytes = (size_t)B * 16 * NLEV * 4;
    const bool tp = ws_size >= w1tBytes;

    dim3 grid((NPTS + PTS_PER_BLOCK - 1) / PTS_PER_BLOCK, B);
    if (tp) {
        transpose_w1<<<dim3(B), dim3(1024), 0, stream>>>(w1, (float*)d_ws);
        hipFuncSetAttribute((const void*)shacira_kernel<true>,
                            hipFuncAttributeMaxDynamicSharedMemorySize, (int)smemBytes);
        shacira_kernel<true><<<grid, dim3(BLOCK), smemBytes, stream>>>(
            x, codebook, w1, (const float*)d_ws, w2, w3, out, lp);
    } else {
        hipFuncSetAttribute((const void*)shacira_kernel<false>,
                            hipFuncAttributeMaxDynamicSharedMemorySize, (int)smemBytes);
        shacira_kernel<false><<<grid, dim3(BLOCK), smemBytes, stream>>>(
            x, codebook, w1, (const float*)0, w2, w3, out, lp);
    }
}